// Round 1
// baseline (520.827 us; speedup 1.0000x reference)
//
#include <hip/hip_runtime.h>
#include <hip/hip_bf16.h>
#include <cstdint>
#include <cstddef>

// Problem constants (fixed by reference): x[8192,4096]f32, Wp[4096,2048]i32(1 byte each),
// scales[4096,32]f32, group=128, out[8192,4096]f32.
#define TOKENS 8192
#define IN_F   4096
#define OUT_F  4096

typedef __bf16 bf16;
typedef bf16  bf16x8 __attribute__((ext_vector_type(8)));
typedef float f32x4  __attribute__((ext_vector_type(4)));

// ---------------- pre-pass 1: x fp32 -> bf16 (memory-bound) ----------------
__global__ void cvt_x_kernel(const float* __restrict__ in, bf16* __restrict__ out) {
    size_t i = ((size_t)blockIdx.x * 256 + threadIdx.x) * 8;
    const float4* p = (const float4*)(in + i);
    float4 a = p[0], b = p[1];
    bf16x8 r;
    r[0] = (bf16)a.x; r[1] = (bf16)a.y; r[2] = (bf16)a.z; r[3] = (bf16)a.w;
    r[4] = (bf16)b.x; r[5] = (bf16)b.y; r[6] = (bf16)b.z; r[7] = (bf16)b.w;
    *(bf16x8*)(out + i) = r;
}

// ---------------- pre-pass 2: int4 W -> bf16 (dequant ONCE, not per M-tile) ----------------
// Wp[n][j] holds one byte: low nibble -> k=2j, high nibble -> k=2j+1; scale = sc[n*32 + (2j)/128].
__global__ void deq_w_kernel(const int* __restrict__ wp, const float* __restrict__ sc,
                             bf16* __restrict__ out) {
    int t  = blockIdx.x * 256 + threadIdx.x;   // 2,097,152 threads, 4 packed each
    int j0 = t << 2;
    int n  = j0 >> 11;                          // /2048
    int g  = (j0 & 2047) >> 6;                  // j/64 == k/128 (all 4 share one group)
    float s = sc[(n << 5) + g];
    int4 p = *(const int4*)(wp + j0);
    bf16x8 r;
    r[0] = (bf16)((float)((p.x & 15) - 8) * s);
    r[1] = (bf16)((float)(((p.x >> 4) & 15) - 8) * s);
    r[2] = (bf16)((float)((p.y & 15) - 8) * s);
    r[3] = (bf16)((float)(((p.y >> 4) & 15) - 8) * s);
    r[4] = (bf16)((float)((p.z & 15) - 8) * s);
    r[5] = (bf16)((float)(((p.z >> 4) & 15) - 8) * s);
    r[6] = (bf16)((float)((p.w & 15) - 8) * s);
    r[7] = (bf16)((float)(((p.w >> 4) & 15) - 8) * s);
    *(bf16x8*)(out + ((size_t)j0 << 1)) = r;    // k = 2*j0, 16B-aligned
}

// ---------------- main GEMM: C[M,N] = A[M,K]_bf16 * B[N,K]_bf16^T (m97 structure) ----------------
// 128x128 C tile, BK=64, 256 threads = 4 waves (2x2), each wave 64x64 = 4x4 of 16x16x32 MFMA.
__global__ void gemm_kernel(const bf16* __restrict__ A, const bf16* __restrict__ B,
                            float* __restrict__ C) {
    __shared__ char smem[32768] __attribute__((aligned(128)));  // sA 16KB | sB 16KB

    const int tid  = threadIdx.x;
    const int lane = tid & 63;
    const int w    = tid >> 6;
    const int mt   = blockIdx.x >> 5;   // 64 M-tiles
    const int nt   = blockIdx.x & 31;   // 32 N-tiles

    // global_load_lds staging: LDS dest is wave-uniform base + lane*16 -> chunk c = (w*4+t)*64+lane
    const char* ga[4]; const char* gb[4]; int ldsoff[4];
#pragma unroll
    for (int t = 0; t < 4; ++t) {
        int c = (w * 4 + t) * 64 + lane;
        int row = c >> 3, kc = c & 7;    // 8 chunks of 16B per 64-wide bf16 row
        ga[t] = (const char*)A + ((size_t)(mt * 128 + row) * IN_F + kc * 8) * 2;
        gb[t] = (const char*)B + ((size_t)(nt * 128 + row) * IN_F + kc * 8) * 2;
        ldsoff[t] = (w * 4 + t) * 1024;
    }

    const int m_lane = lane & 15;
    const int quad   = lane >> 4;
    const int m0     = (w >> 1) * 64;
    const int n0     = (w & 1) * 64;

    f32x4 acc[4][4];
#pragma unroll
    for (int i = 0; i < 4; ++i)
#pragma unroll
        for (int j = 0; j < 4; ++j) acc[i][j] = (f32x4)0.0f;

    const bf16x8* pA = (const bf16x8*)smem;
    const bf16x8* pB = (const bf16x8*)(smem + 16384);

    for (int kt = 0; kt < IN_F / 64; ++kt) {
#pragma unroll
        for (int t = 0; t < 4; ++t) {
            __builtin_amdgcn_global_load_lds(
                (const __attribute__((address_space(1))) void*)(ga[t] + kt * 128),
                (__attribute__((address_space(3))) void*)(smem + ldsoff[t]), 16, 0, 0);
            __builtin_amdgcn_global_load_lds(
                (const __attribute__((address_space(1))) void*)(gb[t] + kt * 128),
                (__attribute__((address_space(3))) void*)(smem + 16384 + ldsoff[t]), 16, 0, 0);
        }
        __syncthreads();   // compiler emits vmcnt(0) drain before barrier (known m97 stall)

#pragma unroll
        for (int h = 0; h < 2; ++h) {
            bf16x8 af[4], bfr[4];
            // A frag: lane holds A[m=lane&15][k=quad*8+j] ; row-major [128][64] LDS
#pragma unroll
            for (int i = 0; i < 4; ++i)
                af[i] = pA[(m0 + i * 16 + m_lane) * 8 + h * 4 + quad];
            // B frag (B^T input): lane holds W[n=lane&15][k=quad*8+j]
#pragma unroll
            for (int j = 0; j < 4; ++j)
                bfr[j] = pB[(n0 + j * 16 + m_lane) * 8 + h * 4 + quad];
#pragma unroll
            for (int i = 0; i < 4; ++i)
#pragma unroll
                for (int j = 0; j < 4; ++j)
                    acc[i][j] = __builtin_amdgcn_mfma_f32_16x16x32_bf16(af[i], bfr[j], acc[i][j], 0, 0, 0);
        }
        __syncthreads();
    }

    // epilogue: C/D layout col=lane&15, row=quad*4+reg (m89-verified)
    size_t crow0 = (size_t)(mt * 128 + m0 + quad * 4) * OUT_F + nt * 128 + n0 + m_lane;
#pragma unroll
    for (int i = 0; i < 4; ++i)
#pragma unroll
        for (int r = 0; r < 4; ++r) {
            float* cp = C + crow0 + (size_t)(i * 16 + r) * OUT_F;
#pragma unroll
            for (int j = 0; j < 4; ++j) cp[j * 16] = acc[i][j][r];
        }
}

// ---------------- fallback (only if ws too small): slow but correct ----------------
__global__ void naive_kernel(const float* __restrict__ x, const int* __restrict__ wp,
                             const float* __restrict__ sc, float* __restrict__ out) {
    int o = blockIdx.x * 256 + threadIdx.x;
    int t = o >> 12, n = o & 4095;
    const float* xr = x + (size_t)t * IN_F;
    const int*   wr = wp + (size_t)n * (IN_F / 2);
    float acc = 0.f;
    for (int g = 0; g < 32; ++g) {
        float s = sc[n * 32 + g];
        float part = 0.f;
        for (int j = 0; j < 64; ++j) {
            int p = wr[g * 64 + j];
            part += xr[g * 128 + 2 * j]     * (float)((p & 15) - 8);
            part += xr[g * 128 + 2 * j + 1] * (float)(((p >> 4) & 15) - 8);
        }
        acc += part * s;
    }
    out[o] = acc;
}

extern "C" void kernel_launch(void* const* d_in, const int* in_sizes, int n_in,
                              void* d_out, int out_size, void* d_ws, size_t ws_size,
                              hipStream_t stream) {
    const float* x  = (const float*)d_in[0];
    const int*   wp = (const int*)d_in[1];
    const float* sc = (const float*)d_in[2];
    float* out = (float*)d_out;

    const size_t xb_bytes = (size_t)TOKENS * IN_F * 2;   // 64 MiB
    const size_t wb_bytes = (size_t)OUT_F * IN_F * 2;    // 32 MiB

    if (ws_size >= xb_bytes + wb_bytes) {
        bf16* xb = (bf16*)d_ws;
        bf16* wb = (bf16*)((char*)d_ws + xb_bytes);
        cvt_x_kernel<<<dim3((TOKENS * IN_F) / (256 * 8)), dim3(256), 0, stream>>>(x, xb);
        deq_w_kernel<<<dim3((OUT_F * (IN_F / 2)) / (256 * 4)), dim3(256), 0, stream>>>(wp, sc, wb);
        gemm_kernel<<<dim3((TOKENS / 128) * (OUT_F / 128)), dim3(256), 0, stream>>>(xb, wb, out);
    } else {
        naive_kernel<<<dim3((TOKENS * OUT_F) / 256), dim3(256), 0, stream>>>(x, wp, sc, out);
    }
}

// Round 2
// 475.924 us; speedup vs baseline: 1.0943x; 1.0943x over previous
//
#include <hip/hip_runtime.h>
#include <hip/hip_bf16.h>
#include <cstdint>
#include <cstddef>

// Problem constants: x[8192,4096]f32, Wp[4096,2048]i32(1 byte each),
// scales[4096,32]f32, group=128, out[8192,4096]f32.
#define TOKENS 8192
#define IN_F   4096
#define OUT_F  4096

typedef __bf16 bf16;
typedef bf16  bf16x8 __attribute__((ext_vector_type(8)));
typedef float f32x4  __attribute__((ext_vector_type(4)));

// ---------------- merged pre-pass: x f32->bf16 AND int4 W -> bf16 ----------------
// blocks [0, 16384): convert x (8 f32 -> 8 bf16 per thread)
// blocks [16384, 24576): dequant W (4 packed bytes -> 8 bf16 per thread)
__global__ void prep_kernel(const float* __restrict__ xin, bf16* __restrict__ xout,
                            const int* __restrict__ wp, const float* __restrict__ sc,
                            bf16* __restrict__ wout) {
    if (blockIdx.x < 16384) {
        size_t i = ((size_t)blockIdx.x * 256 + threadIdx.x) * 8;
        const float4* p = (const float4*)(xin + i);
        float4 a = p[0], b = p[1];
        bf16x8 r;
        r[0] = (bf16)a.x; r[1] = (bf16)a.y; r[2] = (bf16)a.z; r[3] = (bf16)a.w;
        r[4] = (bf16)b.x; r[5] = (bf16)b.y; r[6] = (bf16)b.z; r[7] = (bf16)b.w;
        *(bf16x8*)(xout + i) = r;
    } else {
        int t  = (blockIdx.x - 16384) * 256 + threadIdx.x;
        int j0 = t << 2;                    // first packed byte index
        int n  = j0 >> 11;                  // /2048
        int g  = (j0 & 2047) >> 6;          // group (all 4 bytes share one)
        float s = sc[(n << 5) + g];
        int4 p = *(const int4*)(wp + j0);
        bf16x8 r;
        r[0] = (bf16)((float)((p.x & 15) - 8) * s);
        r[1] = (bf16)((float)(((p.x >> 4) & 15) - 8) * s);
        r[2] = (bf16)((float)((p.y & 15) - 8) * s);
        r[3] = (bf16)((float)(((p.y >> 4) & 15) - 8) * s);
        r[4] = (bf16)((float)((p.z & 15) - 8) * s);
        r[5] = (bf16)((float)(((p.z >> 4) & 15) - 8) * s);
        r[6] = (bf16)((float)((p.w & 15) - 8) * s);
        r[7] = (bf16)((float)(((p.w >> 4) & 15) - 8) * s);
        *(bf16x8*)(wout + ((size_t)j0 << 1)) = r;
    }
}

// ---------------- main GEMM: C[M,N] = A[M,K]_bf16 * B[N,K]_bf16^T ----------------
// 128x128 C tile, BK=64, 256 threads = 4 waves (2x2), each wave 64x64 = 4x4 of 16x16x32 MFMA.
// LDS layout is XOR-swizzled: LDS slot (row, s) holds global 16B-chunk (row, s ^ (row&7)).
// This spreads the 16-lane same-column fragment reads across all 8 column slots
// (2 lanes/bank = free, m136) instead of 16-way conflicting on one bank.
// global_load_lds requires dest = wave-uniform base + lane*16, so the swizzle is
// applied on the GLOBAL address side (per-lane), keeping LDS dests contiguous.
__global__ void gemm_kernel(const bf16* __restrict__ A, const bf16* __restrict__ B,
                            float* __restrict__ C) {
    __shared__ char smem[32768] __attribute__((aligned(128)));  // sA 16KB | sB 16KB

    const int tid  = threadIdx.x;
    const int lane = tid & 63;
    const int w    = tid >> 6;
    const int mt   = blockIdx.x >> 5;   // 64 M-tiles
    const int nt   = blockIdx.x & 31;   // 32 N-tiles

    const char* ga[4]; const char* gb[4]; int ldsoff[4];
#pragma unroll
    for (int t = 0; t < 4; ++t) {
        int c   = (w * 4 + t) * 64 + lane;   // LDS chunk index this lane fills
        int row = c >> 3;
        int g   = (c & 7) ^ (row & 7);       // swizzled global chunk within the 128B row-block
        ga[t] = (const char*)A + (size_t)(mt * 128 + row) * (IN_F * 2) + g * 16;
        gb[t] = (const char*)B + (size_t)(nt * 128 + row) * (IN_F * 2) + g * 16;
        ldsoff[t] = (w * 4 + t) * 1024;
    }

    const int m_lane = lane & 15;
    const int quad   = lane >> 4;
    const int sw     = m_lane & 7;      // read-side swizzle key (row&7 == m_lane&7)
    const int m0     = (w >> 1) * 64;
    const int n0     = (w & 1) * 64;

    f32x4 acc[4][4];
#pragma unroll
    for (int i = 0; i < 4; ++i)
#pragma unroll
        for (int j = 0; j < 4; ++j) acc[i][j] = (f32x4)0.0f;

    const bf16x8* pA = (const bf16x8*)smem;
    const bf16x8* pB = (const bf16x8*)(smem + 16384);

    for (int kt = 0; kt < IN_F / 64; ++kt) {
#pragma unroll
        for (int t = 0; t < 4; ++t) {
            __builtin_amdgcn_global_load_lds(
                (const __attribute__((address_space(1))) void*)(ga[t] + kt * 128),
                (__attribute__((address_space(3))) void*)(smem + ldsoff[t]), 16, 0, 0);
            __builtin_amdgcn_global_load_lds(
                (const __attribute__((address_space(1))) void*)(gb[t] + kt * 128),
                (__attribute__((address_space(3))) void*)(smem + 16384 + ldsoff[t]), 16, 0, 0);
        }
        __syncthreads();

#pragma unroll
        for (int h = 0; h < 2; ++h) {
            const int slot = (h * 4 + quad) ^ sw;   // swizzled column slot
            bf16x8 af[4], bfr[4];
#pragma unroll
            for (int i = 0; i < 4; ++i)
                af[i] = pA[(m0 + i * 16 + m_lane) * 8 + slot];
#pragma unroll
            for (int j = 0; j < 4; ++j)
                bfr[j] = pB[(n0 + j * 16 + m_lane) * 8 + slot];
#pragma unroll
            for (int i = 0; i < 4; ++i)
#pragma unroll
                for (int j = 0; j < 4; ++j)
                    acc[i][j] = __builtin_amdgcn_mfma_f32_16x16x32_bf16(af[i], bfr[j], acc[i][j], 0, 0, 0);
        }
        __syncthreads();
    }

    // epilogue: C/D layout col=lane&15, row=quad*4+reg (m89-verified)
    size_t crow0 = (size_t)(mt * 128 + m0 + quad * 4) * OUT_F + nt * 128 + n0 + m_lane;
#pragma unroll
    for (int i = 0; i < 4; ++i)
#pragma unroll
        for (int r = 0; r < 4; ++r) {
            float* cp = C + crow0 + (size_t)(i * 16 + r) * OUT_F;
#pragma unroll
            for (int j = 0; j < 4; ++j) cp[j * 16] = acc[i][j][r];
        }
}

// ---------------- fallback (only if ws too small): slow but correct ----------------
__global__ void naive_kernel(const float* __restrict__ x, const int* __restrict__ wp,
                             const float* __restrict__ sc, float* __restrict__ out) {
    int o = blockIdx.x * 256 + threadIdx.x;
    int t = o >> 12, n = o & 4095;
    const float* xr = x + (size_t)t * IN_F;
    const int*   wr = wp + (size_t)n * (IN_F / 2);
    float acc = 0.f;
    for (int g = 0; g < 32; ++g) {
        float s = sc[n * 32 + g];
        float part = 0.f;
        for (int j = 0; j < 64; ++j) {
            int p = wr[g * 64 + j];
            part += xr[g * 128 + 2 * j]     * (float)((p & 15) - 8);
            part += xr[g * 128 + 2 * j + 1] * (float)(((p >> 4) & 15) - 8);
        }
        acc += part * s;
    }
    out[o] = acc;
}

extern "C" void kernel_launch(void* const* d_in, const int* in_sizes, int n_in,
                              void* d_out, int out_size, void* d_ws, size_t ws_size,
                              hipStream_t stream) {
    const float* x  = (const float*)d_in[0];
    const int*   wp = (const int*)d_in[1];
    const float* sc = (const float*)d_in[2];
    float* out = (float*)d_out;

    const size_t xb_bytes = (size_t)TOKENS * IN_F * 2;   // 64 MiB
    const size_t wb_bytes = (size_t)OUT_F * IN_F * 2;    // 32 MiB

    if (ws_size >= xb_bytes + wb_bytes) {
        bf16* xb = (bf16*)d_ws;
        bf16* wb = (bf16*)((char*)d_ws + xb_bytes);
        prep_kernel<<<dim3(16384 + 8192), dim3(256), 0, stream>>>(x, xb, wp, sc, wb);
        gemm_kernel<<<dim3((TOKENS / 128) * (OUT_F / 128)), dim3(256), 0, stream>>>(xb, wb, out);
    } else {
        naive_kernel<<<dim3((TOKENS * OUT_F) / 256), dim3(256), 0, stream>>>(x, wp, sc, out);
    }
}